// Round 18
// baseline (142.121 us; speedup 1.0000x reference)
//
#include <hip/hip_runtime.h>
#include <hip/hip_cooperative_groups.h>

#define CCH 128
#define SP  4096          // 64*64 spatial positions per (b,c)
#define BROWS 10          // band rows rb in [0,10)
#define RSTR 76           // g rb-stride (floats): rows at bank offsets {0,12,24}
#define BSZ2 (BROWS * RSTR)  // 760 floats per band
#define GOFF 16           // g data starts at 16 (64B-aligned); g[0] = sentinel 0
#define GTOT (GOFF + 9 * BSZ2)   // 6856 floats = 27.4 KB
#define T16_OFF 65536     // byte offset of the u16 (s=8) table in d_ws
#define TBLK 80           // table-generator blocks (fallback path)
#define XTSTR 136         // LDS x_t halfword stride (272B rows)
#define LOG2E 1.4426950408889634f

typedef __attribute__((ext_vector_type(8))) short bf16x8;   // 8 bf16 = 4 VGPRs
typedef __attribute__((ext_vector_type(4))) float f32x4;

__device__ __forceinline__ float sigmoidf_(float z) {
  return 1.0f / (1.0f + __expf(-z));
}

__device__ __forceinline__ unsigned short bf16rne(float f) {
  union { float f; unsigned u; } v; v.f = f;
  return (unsigned short)((v.u + 0x7fffu + ((v.u >> 16) & 1u)) >> 16);
}

// Band-local gather offset for tap s at output wh (g layout [s][rb][sh]):
// GOFF + s*760 + rb*76 + sh, or 0 (sentinel g[0]=0) when source is OOB.
__device__ __forceinline__ int tap_off(int s, int wh) {
  int q  = (s << 12) + wh;     // flat index into torch's reinterpreted view
  int wi = q / 576;  int r  = q - wi * 576;
  int hi = r / 9;    int kk = r - hi * 9;
  int di = kk / 3,   dj = kk - di * 3;
  int sw = wi + di - 1, sh = hi + dj - 1;
  bool valid = ((unsigned)sw < 64u) & ((unsigned)sh < 64u);
  int wilo = (s * 64) / 9;     // first source row of band s
  int rb = sw - wilo + 1;      // in [0,10) for valid sw
  return valid ? (GOFF + s * BSZ2 + rb * RSTR + sh) : 0;
}

// ---------------- fused single-dispatch kernel (cooperative) ----------------
// Phase T: gather tables. Phase A: MFMA conv y = w @ x -> d_out.
// grid.sync() + device fences (y is read cross-XCD within this dispatch).
// Phase B: attnmax overwrites each y-plane with the output.
__global__ __launch_bounds__(256) void k_fused(
    const float* __restrict__ x, const float* __restrict__ attn_w,
    const float* __restrict__ se_param, const float* __restrict__ attn_b,
    float* __restrict__ y, unsigned* __restrict__ t32,
    unsigned short* __restrict__ t16, int B) {
  cooperative_groups::grid_group grid = cooperative_groups::this_grid();
  __shared__ __align__(16) char smem[GTOT * 4];   // union: x_t (8.7KB) / g (27.4KB)
  __shared__ float se9[16], sl9[16];

  int nblk = gridDim.x;
  int lane = threadIdx.x & 63, wv = threadIdx.x >> 6;

  // ---- Phase T: tables (grid-stride; 20480 entries) ----
  for (int ti = blockIdx.x * 256 + threadIdx.x; ti < 5 * SP; ti += nblk * 256) {
    if (ti < 4 * SP) {
      int wh = ti >> 2, j = ti & 3;        // uint4-per-wh packing
      unsigned lo = (unsigned)tap_off(2 * j, wh);
      unsigned hi = (unsigned)tap_off(2 * j + 1, wh);
      t32[ti] = lo | (hi << 16);
    } else {
      int wh = ti & (SP - 1);
      t16[wh] = (unsigned short)tap_off(8, wh);
    }
  }
  if (threadIdx.x < 9) {
    float se = sigmoidf_(se_param[threadIdx.x]);
    se9[threadIdx.x] = se;
    sl9[threadIdx.x] = -se * LOG2E;
  }

  // ---- Phase A: conv. A-frags once (weights shared by all units). ----
  bf16x8 afrag[2][4];
#pragma unroll
  for (int ot = 0; ot < 2; ot++)
#pragma unroll
    for (int ks = 0; ks < 4; ks++) {
      int o = (wv << 5) + (ot << 4) + (lane & 15);
      int k = (ks << 5) + ((lane >> 4) << 3);
      const float4* wp = (const float4*)&attn_w[(o << 7) + k];
      float4 a0 = wp[0], a1 = wp[1];
      bf16x8 f;
      f[0] = (short)bf16rne(a0.x); f[1] = (short)bf16rne(a0.y);
      f[2] = (short)bf16rne(a0.z); f[3] = (short)bf16rne(a0.w);
      f[4] = (short)bf16rne(a1.x); f[5] = (short)bf16rne(a1.y);
      f[6] = (short)bf16rne(a1.z); f[7] = (short)bf16rne(a1.w);
      afrag[ot][ks] = f;
    }

  unsigned short* x_t = (unsigned short*)smem;
  int n_st = threadIdx.x & 31;
  int c_st = (threadIdx.x >> 5) << 2;

  for (int u = blockIdx.x; u < B * 128; u += nblk) {
    int b = u >> 7, nb = u & 127;
    const float* xpb = x + ((size_t)b << 19) + (nb << 5);
    float xv[16];
#pragma unroll
    for (int g = 0; g < 4; g++) {
      int c0 = c_st + (g << 5);
#pragma unroll
      for (int i = 0; i < 4; i++)
        xv[g * 4 + i] = xpb[((size_t)(c0 + i) << 12) + n_st];
    }
    __syncthreads();   // protect previous unit's x_t reads
#pragma unroll
    for (int g = 0; g < 4; g++) {
      int c0 = c_st + (g << 5);
      union { unsigned short s[2]; unsigned u; } p0, p1;
      p0.s[0] = bf16rne(xv[g * 4 + 0]); p0.s[1] = bf16rne(xv[g * 4 + 1]);
      p1.s[0] = bf16rne(xv[g * 4 + 2]); p1.s[1] = bf16rne(xv[g * 4 + 3]);
      *(uint2*)&x_t[n_st * XTSTR + c0] = make_uint2(p0.u, p1.u);
    }
    __syncthreads();

    f32x4 acc[2][2] = {};
#pragma unroll
    for (int ks = 0; ks < 4; ks++) {
      bf16x8 bfrag[2];
#pragma unroll
      for (int nt = 0; nt < 2; nt++) {
        int n = (nt << 4) + (lane & 15);
        int k = (ks << 5) + ((lane >> 4) << 3);
        bfrag[nt] = *(const bf16x8*)&x_t[n * XTSTR + k];   // ds_read_b128
      }
#pragma unroll
      for (int ot = 0; ot < 2; ot++)
#pragma unroll
        for (int nt = 0; nt < 2; nt++)
          acc[ot][nt] = __builtin_amdgcn_mfma_f32_16x16x32_bf16(
              afrag[ot][ks], bfrag[nt], acc[ot][nt], 0, 0, 0);
    }

    float* yb = y + ((size_t)b << 19) + (nb << 5);
#pragma unroll
    for (int ot = 0; ot < 2; ot++) {
      int ob = (wv << 5) + (ot << 4) + ((lane >> 4) << 2);
#pragma unroll
      for (int nt = 0; nt < 2; nt++) {
        int n = (nt << 4) + (lane & 15);
#pragma unroll
        for (int r = 0; r < 4; r++)
          yb[((size_t)(ob + r) << 12) + n] = acc[ot][nt][r];
      }
    }
  }

  // ---- grid-wide sync: y + tables must be visible cross-XCD ----
  __syncthreads();
  __threadfence();       // release (drains stores, writes back L2)
  grid.sync();
  __threadfence();       // acquire (invalidates stale lines)

  // ---- Phase B: attnmax ----
  float* g = (float*)smem;
  for (int bc = blockIdx.x; bc < B * 128; bc += nblk) {
    int c = bc & (CCH - 1);
    const float* xp = x + ((size_t)bc << 12);
    float*       yp = y + ((size_t)bc << 12);
    float ab  = attn_b[c];
    float abl = -ab * LOG2E;
    __syncthreads();     // protect previous plane's g reads
    if (threadIdx.x == 0) g[0] = 0.0f;

    // Phase 1: 1440 float4 units -> (s, rb, sh0); rg = wilo(s)-1+rb.
    for (int f = threadIdx.x; f < 9 * BROWS * 16; f += 256) {
      int s   = f / 160;
      int rem = f - s * 160;
      int rb  = rem >> 4, sh0 = (rem & 15) << 2;
      int rg  = ((s * 64 * 58255) >> 19) - 1 + rb;   // wilo(s) = (s*64)/9
      float4 gv = make_float4(0.0f, 0.0f, 0.0f, 0.0f);
      if ((unsigned)rg < 64u) {
        float se = se9[s], sl = sl9[s];
        float4 xx = *(const float4*)&xp[(rg << 6) + sh0];
        float4 yy = *(const float4*)&yp[(rg << 6) + sh0];
        gv.x = se * xx.x * __builtin_amdgcn_rcpf(1.0f + exp2f(fmaf(yy.x, sl, abl)));
        gv.y = se * xx.y * __builtin_amdgcn_rcpf(1.0f + exp2f(fmaf(yy.y, sl, abl)));
        gv.z = se * xx.z * __builtin_amdgcn_rcpf(1.0f + exp2f(fmaf(yy.z, sl, abl)));
        gv.w = se * xx.w * __builtin_amdgcn_rcpf(1.0f + exp2f(fmaf(yy.w, sl, abl)));
      }
      *(float4*)&g[GOFF + s * BSZ2 + rb * RSTR + sh0] = gv;
    }
    __syncthreads();

    // Phase 2: gather + max; overwrite the y-plane with the result.
    for (int k = 0; k < 16; k++) {
      int wh = (k << 8) | threadIdx.x;
      uint4 p = ((const uint4*)t32)[wh];
      int p8  = t16[wh];
      float m0 = fmaxf(g[p.x & 0xffffu], g[p.x >> 16]);
      float m1 = fmaxf(g[p.y & 0xffffu], g[p.y >> 16]);
      float m2 = fmaxf(g[p.z & 0xffffu], g[p.z >> 16]);
      float m3 = fmaxf(g[p.w & 0xffffu], g[p.w >> 16]);
      yp[wh] = fmaxf(fmaxf(fmaxf(m0, m1), fmaxf(m2, m3)), g[p8]);
    }
  }
}

// ---------------- fallback path (R16, two dispatches) ----------------
template <bool WS>
__global__ __launch_bounds__(256) void k_conv(
    const float* __restrict__ x, const float* __restrict__ attn_w,
    float* __restrict__ y, unsigned* __restrict__ t32,
    unsigned short* __restrict__ t16) {
  int bid = blockIdx.x;
  if (WS) {
    if (bid < TBLK) {
      int i = bid * 256 + threadIdx.x;
      if (i < 4 * SP) {
        int wh = i >> 2, j = i & 3;
        unsigned lo = (unsigned)tap_off(2 * j, wh);
        unsigned hi = (unsigned)tap_off(2 * j + 1, wh);
        t32[i] = lo | (hi << 16);
      } else if (i < 5 * SP) {
        int wh = i & (SP - 1);
        t16[wh] = (unsigned short)tap_off(8, wh);
      }
      return;
    }
    bid -= TBLK;
  }

  __shared__ unsigned short x_t[32 * XTSTR];
  int b  = bid >> 7;
  int nb = bid & 127;
  int lane = threadIdx.x & 63, wv = threadIdx.x >> 6;

  const float* xpb = x + ((size_t)b << 19) + (nb << 5);
  int n_st  = threadIdx.x & 31;
  int c_st  = (threadIdx.x >> 5) << 2;
  float xv[16];
#pragma unroll
  for (int g = 0; g < 4; g++) {
    int c0 = c_st + (g << 5);
#pragma unroll
    for (int i = 0; i < 4; i++)
      xv[g * 4 + i] = xpb[((size_t)(c0 + i) << 12) + n_st];
  }

  bf16x8 afrag[2][4];
#pragma unroll
  for (int ot = 0; ot < 2; ot++)
#pragma unroll
    for (int ks = 0; ks < 4; ks++) {
      int o = (wv << 5) + (ot << 4) + (lane & 15);
      int k = (ks << 5) + ((lane >> 4) << 3);
      const float4* wp = (const float4*)&attn_w[(o << 7) + k];
      float4 a0 = wp[0], a1 = wp[1];
      bf16x8 f;
      f[0] = (short)bf16rne(a0.x); f[1] = (short)bf16rne(a0.y);
      f[2] = (short)bf16rne(a0.z); f[3] = (short)bf16rne(a0.w);
      f[4] = (short)bf16rne(a1.x); f[5] = (short)bf16rne(a1.y);
      f[6] = (short)bf16rne(a1.z); f[7] = (short)bf16rne(a1.w);
      afrag[ot][ks] = f;
    }

#pragma unroll
  for (int g = 0; g < 4; g++) {
    int c0 = c_st + (g << 5);
    union { unsigned short s[2]; unsigned u; } p0, p1;
    p0.s[0] = bf16rne(xv[g * 4 + 0]); p0.s[1] = bf16rne(xv[g * 4 + 1]);
    p1.s[0] = bf16rne(xv[g * 4 + 2]); p1.s[1] = bf16rne(xv[g * 4 + 3]);
    *(uint2*)&x_t[n_st * XTSTR + c0] = make_uint2(p0.u, p1.u);
  }
  __syncthreads();

  f32x4 acc[2][2] = {};
#pragma unroll
  for (int ks = 0; ks < 4; ks++) {
    bf16x8 bfrag[2];
#pragma unroll
    for (int nt = 0; nt < 2; nt++) {
      int n = (nt << 4) + (lane & 15);
      int k = (ks << 5) + ((lane >> 4) << 3);
      bfrag[nt] = *(const bf16x8*)&x_t[n * XTSTR + k];
    }
#pragma unroll
    for (int ot = 0; ot < 2; ot++)
#pragma unroll
      for (int nt = 0; nt < 2; nt++)
        acc[ot][nt] = __builtin_amdgcn_mfma_f32_16x16x32_bf16(
            afrag[ot][ks], bfrag[nt], acc[ot][nt], 0, 0, 0);
  }

  float* yb = y + ((size_t)b << 19) + (nb << 5);
#pragma unroll
  for (int ot = 0; ot < 2; ot++) {
    int ob = (wv << 5) + (ot << 4) + ((lane >> 4) << 2);
#pragma unroll
    for (int nt = 0; nt < 2; nt++) {
      int n = (nt << 4) + (lane & 15);
#pragma unroll
      for (int r = 0; r < 4; r++)
        yb[((size_t)(ob + r) << 12) + n] = acc[ot][nt][r];
    }
  }
}

template <bool TBL>
__global__ __launch_bounds__(256) void k_attnmax(
    const float* __restrict__ x, float* __restrict__ yo,
    const float* __restrict__ se_param, const float* __restrict__ attn_b,
    const uint4* __restrict__ t32, const unsigned short* __restrict__ t16) {
  __shared__ float g[GTOT];
  __shared__ float se9[16], sl9[16];

  int bc = blockIdx.x;
  int c  = bc & (CCH - 1);
  const float* xp = x  + ((size_t)bc << 12);
  float*       yp = yo + ((size_t)bc << 12);

  if (threadIdx.x < 9) {
    float se = sigmoidf_(se_param[threadIdx.x]);
    se9[threadIdx.x] = se;
    sl9[threadIdx.x] = -se * LOG2E;
  }
  if (threadIdx.x == 0) g[0] = 0.0f;
  float ab  = attn_b[c];
  float abl = -ab * LOG2E;
  __syncthreads();

  for (int f = threadIdx.x; f < 9 * BROWS * 16; f += 256) {
    int s   = f / 160;
    int rem = f - s * 160;
    int rb  = rem >> 4, sh0 = (rem & 15) << 2;
    int rg  = ((s * 64 * 58255) >> 19) - 1 + rb;
    float4 gv = make_float4(0.0f, 0.0f, 0.0f, 0.0f);
    if ((unsigned)rg < 64u) {
      float se = se9[s], sl = sl9[s];
      float4 xx = *(const float4*)&xp[(rg << 6) + sh0];
      float4 yy = *(const float4*)&yp[(rg << 6) + sh0];
      gv.x = se * xx.x * __builtin_amdgcn_rcpf(1.0f + exp2f(fmaf(yy.x, sl, abl)));
      gv.y = se * xx.y * __builtin_amdgcn_rcpf(1.0f + exp2f(fmaf(yy.y, sl, abl)));
      gv.z = se * xx.z * __builtin_amdgcn_rcpf(1.0f + exp2f(fmaf(yy.z, sl, abl)));
      gv.w = se * xx.w * __builtin_amdgcn_rcpf(1.0f + exp2f(fmaf(yy.w, sl, abl)));
    }
    *(float4*)&g[GOFF + s * BSZ2 + rb * RSTR + sh0] = gv;
  }
  __syncthreads();

  for (int k = 0; k < 16; k++) {
    int wh = (k << 8) | threadIdx.x;
    float m;
    if (TBL) {
      uint4 p = t32[wh];
      int p8  = t16[wh];
      float m0 = fmaxf(g[p.x & 0xffffu], g[p.x >> 16]);
      float m1 = fmaxf(g[p.y & 0xffffu], g[p.y >> 16]);
      float m2 = fmaxf(g[p.z & 0xffffu], g[p.z >> 16]);
      float m3 = fmaxf(g[p.w & 0xffffu], g[p.w >> 16]);
      m = fmaxf(fmaxf(fmaxf(m0, m1), fmaxf(m2, m3)), g[p8]);
    } else {
      m = 0.0f;
#pragma unroll
      for (int s = 0; s < 9; s++) m = fmaxf(m, g[tap_off(s, wh)]);
    }
    yp[wh] = m;
  }
}

extern "C" void kernel_launch(void* const* d_in, const int* in_sizes, int n_in,
                              void* d_out, int out_size, void* d_ws, size_t ws_size,
                              hipStream_t stream) {
  const float* x        = (const float*)d_in[0];
  const float* se_param = (const float*)d_in[1];
  const float* attn_w   = (const float*)d_in[2];
  const float* attn_b   = (const float*)d_in[3];
  float* out = (float*)d_out;

  int B = in_sizes[0] / (CCH * SP);
  unsigned* t32       = (unsigned*)d_ws;
  unsigned short* t16 = (unsigned short*)((char*)d_ws + T16_OFF);
  bool use_ws = ws_size >= (size_t)(T16_OFF + SP * sizeof(unsigned short));

  bool launched = false;
  if (use_ws) {
    // Size the cooperative grid to guaranteed co-residency.
    int dev = 0, numCU = 0, maxPerCU = 0;
    (void)hipGetDevice(&dev);
    (void)hipDeviceGetAttribute(&numCU, hipDeviceAttributeMultiprocessorCount,
                                dev);
    if (hipOccupancyMaxActiveBlocksPerMultiprocessor(&maxPerCU, k_fused, 256, 0)
            != hipSuccess || maxPerCU < 1)
      maxPerCU = 2;   // conservative: LDS 27.4KB -> >=2 blocks/CU always fits
    if (numCU <= 0) numCU = 256;
    int grid = maxPerCU * numCU;
    if (grid > B * 128) grid = B * 128;

    void* args[] = {(void*)&x, (void*)&attn_w, (void*)&se_param,
                    (void*)&attn_b, (void*)&out, (void*)&t32, (void*)&t16,
                    (void*)&B};
    hipError_t e = hipLaunchCooperativeKernel((void*)k_fused, dim3(grid),
                                              dim3(256), args, 0, stream);
    launched = (e == hipSuccess);
  }

  if (!launched) {
    if (use_ws) {
      k_conv<true><<<dim3(TBLK + B * 128), dim3(256), 0, stream>>>(
          x, attn_w, out, t32, t16);
      k_attnmax<true><<<dim3(B * CCH), dim3(256), 0, stream>>>(
          x, out, se_param, attn_b, (const uint4*)t32, t16);
    } else {
      k_conv<false><<<dim3(B * 128), dim3(256), 0, stream>>>(
          x, attn_w, out, nullptr, nullptr);
      k_attnmax<false><<<dim3(B * CCH), dim3(256), 0, stream>>>(
          x, out, se_param, attn_b, nullptr, nullptr);
    }
  }
}

// Round 19
// 34.394 us; speedup vs baseline: 4.1322x; 4.1322x over previous
//
#include <hip/hip_runtime.h>

#define CCH 128
#define SP  4096          // 64*64 spatial positions per (b,c)
#define BROWS 10          // band rows rb in [0,10)
#define RSTR 76           // g rb-stride (floats): rows at bank offsets {0,12,24}
#define BSZ2 (BROWS * RSTR)  // 760 floats per band
#define GOFF 16           // g data starts at 16 (64B-aligned); g[0] = sentinel 0
#define GTOT (GOFF + 9 * BSZ2)   // 6856 floats = 27.4 KB
#define T16_OFF 65536     // byte offset of the u16 (s=8) table in d_ws
#define Y_OFFB 73728      // byte offset of bf16 y[b][o][n] in d_ws (8.4 MB)
#define TBLK 80           // table-generator blocks fused into conv grid
#define XTSTR 136         // LDS x_t halfword stride (272B rows)
#define LOG2E 1.4426950408889634f

typedef __attribute__((ext_vector_type(8))) short bf16x8;   // 8 bf16 = 4 VGPRs
typedef __attribute__((ext_vector_type(4))) float f32x4;

__device__ __forceinline__ float sigmoidf_(float z) {
  return 1.0f / (1.0f + __expf(-z));
}

__device__ __forceinline__ unsigned short bf16rne(float f) {
  union { float f; unsigned u; } v; v.f = f;
  return (unsigned short)((v.u + 0x7fffu + ((v.u >> 16) & 1u)) >> 16);
}

__device__ __forceinline__ float bf2f(unsigned short u) {
  union { unsigned u; float f; } v; v.u = (unsigned)u << 16;
  return v.f;
}

// Band-local gather offset for tap s at output wh (g layout [s][rb][sh]):
// GOFF + s*760 + rb*76 + sh, or 0 (sentinel g[0]=0) when source is OOB.
__device__ __forceinline__ int tap_off(int s, int wh) {
  int q  = (s << 12) + wh;     // flat index into torch's reinterpreted view
  int wi = q / 576;  int r  = q - wi * 576;
  int hi = r / 9;    int kk = r - hi * 9;
  int di = kk / 3,   dj = kk - di * 3;
  int sw = wi + di - 1, sh = hi + dj - 1;
  bool valid = ((unsigned)sw < 64u) & ((unsigned)sh < 64u);
  int wilo = (s * 64) / 9;     // first source row of band s
  int rb = sw - wilo + 1;      // in [0,10) for valid sw
  return valid ? (GOFF + s * BSZ2 + rb * RSTR + sh) : 0;
}

// Blocks [0,TBLK): gather tables. Blocks [TBLK,..): MFMA conv, y -> bf16 d_ws.
// Conv block = 128o x 16n, 4 waves; wave = 32o x 16n = 2 o-tiles, 4 k-steps.
// Grid 2048 -> ~8 blocks/CU (LDS 4.4KB, ~55 VGPR) for staging-latency hiding.
// A/B share k-slot indexing -> invariant to HW k-permutation.
// C/D (m89): col = lane&15 (n), row = (lane>>4)*4 + reg (o).
__global__ __launch_bounds__(256) void k_conv(
    const float* __restrict__ x, const float* __restrict__ attn_w,
    unsigned short* __restrict__ ybf, unsigned* __restrict__ t32,
    unsigned short* __restrict__ t16) {
  int bid = blockIdx.x;
  if (bid < TBLK) {   // table generation: 20480 entries, one per thread
    int i = bid * 256 + threadIdx.x;
    if (i < 4 * SP) {
      int wh = i >> 2, j = i & 3;         // uint4-per-wh packing
      unsigned lo = (unsigned)tap_off(2 * j, wh);
      unsigned hi = (unsigned)tap_off(2 * j + 1, wh);
      t32[i] = lo | (hi << 16);
    } else if (i < 5 * SP) {
      int wh = i & (SP - 1);
      t16[wh] = (unsigned short)tap_off(8, wh);
    }
    return;
  }
  bid -= TBLK;

  __shared__ unsigned short x_t[16 * XTSTR];   // 4352 B

  int b  = bid >> 8;
  int nb = bid & 255;                          // 16n slab
  int lane = threadIdx.x & 63, wv = threadIdx.x >> 6;

  // Staging loads first: 8 dwords/thread (lanes 0-15 consecutive n = 64B segs).
  const float* xpb = x + ((size_t)b << 19) + (nb << 4);
  int n_st = threadIdx.x & 15;
  int c_st = (threadIdx.x >> 4) << 3;          // 0..120 step 8
  float xv[8];
#pragma unroll
  for (int i = 0; i < 8; i++)
    xv[i] = xpb[((size_t)(c_st + i) << 12) + n_st];

  // A-fragments from fp32 w (L2-hot 64KB): lane l holds
  // A[o = ot*16 + (l&15)][k = ks*32 + (l>>4)*8 .. +7], converted to bf16.
  bf16x8 afrag[2][4];
#pragma unroll
  for (int ot = 0; ot < 2; ot++)
#pragma unroll
    for (int ks = 0; ks < 4; ks++) {
      int o = (wv << 5) + (ot << 4) + (lane & 15);
      int k = (ks << 5) + ((lane >> 4) << 3);
      const float4* wp = (const float4*)&attn_w[(o << 7) + k];
      float4 a0 = wp[0], a1 = wp[1];
      bf16x8 f;
      f[0] = (short)bf16rne(a0.x); f[1] = (short)bf16rne(a0.y);
      f[2] = (short)bf16rne(a0.z); f[3] = (short)bf16rne(a0.w);
      f[4] = (short)bf16rne(a1.x); f[5] = (short)bf16rne(a1.y);
      f[6] = (short)bf16rne(a1.z); f[7] = (short)bf16rne(a1.w);
      afrag[ot][ks] = f;
    }

  // Pack 8 staged values -> one uint4 LDS write (x_t[n][c_st..c_st+7]).
  union { unsigned short s[8]; uint4 q; } pk;
#pragma unroll
  for (int i = 0; i < 8; i++) pk.s[i] = bf16rne(xv[i]);
  *(uint4*)&x_t[n_st * XTSTR + c_st] = pk.q;
  __syncthreads();

  f32x4 acc[2] = {};
#pragma unroll
  for (int ks = 0; ks < 4; ks++) {
    int n = lane & 15;
    int k = (ks << 5) + ((lane >> 4) << 3);
    bf16x8 bfrag = *(const bf16x8*)&x_t[n * XTSTR + k];   // ds_read_b128
#pragma unroll
    for (int ot = 0; ot < 2; ot++)
      acc[ot] = __builtin_amdgcn_mfma_f32_16x16x32_bf16(
          afrag[ot][ks], bfrag, acc[ot], 0, 0, 0);
  }

  // Epilogue: acc[ot][r] -> bf16 y[o][n], o = base + (lane>>4)*4 + r.
  unsigned short* yb = ybf + ((size_t)b << 19) + (nb << 4);
  int n = lane & 15;
#pragma unroll
  for (int ot = 0; ot < 2; ot++) {
    int ob = (wv << 5) + (ot << 4) + ((lane >> 4) << 2);
#pragma unroll
    for (int r = 0; r < 4; r++)
      yb[((size_t)(ob + r) << 12) + n] = bf16rne(acc[ot][r]);
  }
}

// out[b,c,wh] = max_s G_s[src(s,wh)], G_s[p] = se[s]*x[p]*sigmoid(se[s]*y[p]+ab).
// y read as bf16 from d_ws; result written once to d_out.
__global__ __launch_bounds__(256) void k_attnmax(
    const float* __restrict__ x, const unsigned short* __restrict__ ybf,
    float* __restrict__ out,
    const float* __restrict__ se_param, const float* __restrict__ attn_b,
    const uint4* __restrict__ t32, const unsigned short* __restrict__ t16) {
  __shared__ float g[GTOT];
  __shared__ float se9[16], sl9[16];

  int bc = blockIdx.x;            // b*128 + c
  int c  = bc & (CCH - 1);
  const float* xp = x + ((size_t)bc << 12);
  const unsigned short* yp = ybf + ((size_t)bc << 12);
  float* op = out + ((size_t)bc << 12);

  if (threadIdx.x < 9) {
    float se = sigmoidf_(se_param[threadIdx.x]);
    se9[threadIdx.x] = se;
    sl9[threadIdx.x] = -se * LOG2E;
  }
  if (threadIdx.x == 0) g[0] = 0.0f;
  float ab  = attn_b[c];
  float abl = -ab * LOG2E;
  __syncthreads();

  // Phase 1: 1440 float4 units -> (s, rb, sh0). Source row rg = wilo(s)-1+rb.
  for (int f = threadIdx.x; f < 9 * BROWS * 16; f += 256) {
    int s   = f / 160;
    int rem = f - s * 160;
    int rb  = rem >> 4, sh0 = (rem & 15) << 2;
    int rg  = ((s * 64 * 58255) >> 19) - 1 + rb;   // wilo(s) = (s*64)/9
    float4 gv = make_float4(0.0f, 0.0f, 0.0f, 0.0f);
    if ((unsigned)rg < 64u) {
      float se = se9[s], sl = sl9[s];
      float4 xx = *(const float4*)&xp[(rg << 6) + sh0];     // coalesced
      ushort4 yu = *(const ushort4*)&yp[(rg << 6) + sh0];   // bf16 y
      gv.x = se * xx.x * __builtin_amdgcn_rcpf(1.0f + exp2f(fmaf(bf2f(yu.x), sl, abl)));
      gv.y = se * xx.y * __builtin_amdgcn_rcpf(1.0f + exp2f(fmaf(bf2f(yu.y), sl, abl)));
      gv.z = se * xx.z * __builtin_amdgcn_rcpf(1.0f + exp2f(fmaf(bf2f(yu.z), sl, abl)));
      gv.w = se * xx.w * __builtin_amdgcn_rcpf(1.0f + exp2f(fmaf(bf2f(yu.w), sl, abl)));
    }
    *(float4*)&g[GOFF + s * BSZ2 + rb * RSTR + sh0] = gv;   // b128, aligned
  }
  __syncthreads();

  // Phase 2: gather + max -> d_out.
  for (int k = 0; k < 16; k++) {
    int wh = (k << 8) | threadIdx.x;
    uint4 p = t32[wh];                 // 16B coalesced: taps 0..7
    int p8  = t16[wh];
    float m0 = fmaxf(g[p.x & 0xffffu], g[p.x >> 16]);
    float m1 = fmaxf(g[p.y & 0xffffu], g[p.y >> 16]);
    float m2 = fmaxf(g[p.z & 0xffffu], g[p.z >> 16]);
    float m3 = fmaxf(g[p.w & 0xffffu], g[p.w >> 16]);
    op[wh] = fmaxf(fmaxf(fmaxf(m0, m1), fmaxf(m2, m3)), g[p8]);
  }
}

// ---------------- fallback path (no workspace): fp32 y via d_out ----------------
__global__ __launch_bounds__(256) void k_conv_fb(
    const float* __restrict__ x, const float* __restrict__ attn_w,
    float* __restrict__ y) {
  __shared__ unsigned short x_t[16 * XTSTR];
  int bid = blockIdx.x;
  int b  = bid >> 8;
  int nb = bid & 255;
  int lane = threadIdx.x & 63, wv = threadIdx.x >> 6;

  const float* xpb = x + ((size_t)b << 19) + (nb << 4);
  int n_st = threadIdx.x & 15;
  int c_st = (threadIdx.x >> 4) << 3;
  float xv[8];
#pragma unroll
  for (int i = 0; i < 8; i++)
    xv[i] = xpb[((size_t)(c_st + i) << 12) + n_st];

  bf16x8 afrag[2][4];
#pragma unroll
  for (int ot = 0; ot < 2; ot++)
#pragma unroll
    for (int ks = 0; ks < 4; ks++) {
      int o = (wv << 5) + (ot << 4) + (lane & 15);
      int k = (ks << 5) + ((lane >> 4) << 3);
      const float4* wp = (const float4*)&attn_w[(o << 7) + k];
      float4 a0 = wp[0], a1 = wp[1];
      bf16x8 f;
      f[0] = (short)bf16rne(a0.x); f[1] = (short)bf16rne(a0.y);
      f[2] = (short)bf16rne(a0.z); f[3] = (short)bf16rne(a0.w);
      f[4] = (short)bf16rne(a1.x); f[5] = (short)bf16rne(a1.y);
      f[6] = (short)bf16rne(a1.z); f[7] = (short)bf16rne(a1.w);
      afrag[ot][ks] = f;
    }

  union { unsigned short s[8]; uint4 q; } pk;
#pragma unroll
  for (int i = 0; i < 8; i++) pk.s[i] = bf16rne(xv[i]);
  *(uint4*)&x_t[n_st * XTSTR + c_st] = pk.q;
  __syncthreads();

  f32x4 acc[2] = {};
#pragma unroll
  for (int ks = 0; ks < 4; ks++) {
    int n = lane & 15;
    int k = (ks << 5) + ((lane >> 4) << 3);
    bf16x8 bfrag = *(const bf16x8*)&x_t[n * XTSTR + k];
#pragma unroll
    for (int ot = 0; ot < 2; ot++)
      acc[ot] = __builtin_amdgcn_mfma_f32_16x16x32_bf16(
          afrag[ot][ks], bfrag, acc[ot], 0, 0, 0);
  }

  float* yb = y + ((size_t)b << 19) + (nb << 4);
  int n = lane & 15;
#pragma unroll
  for (int ot = 0; ot < 2; ot++) {
    int ob = (wv << 5) + (ot << 4) + ((lane >> 4) << 2);
#pragma unroll
    for (int r = 0; r < 4; r++)
      yb[((size_t)(ob + r) << 12) + n] = acc[ot][r];
  }
}

__global__ __launch_bounds__(256) void k_attnmax_fb(
    const float* __restrict__ x, float* __restrict__ yo,
    const float* __restrict__ se_param, const float* __restrict__ attn_b) {
  __shared__ float g[GTOT];
  __shared__ float se9[16], sl9[16];

  int bc = blockIdx.x;
  int c  = bc & (CCH - 1);
  const float* xp = x  + ((size_t)bc << 12);
  float*       yp = yo + ((size_t)bc << 12);

  if (threadIdx.x < 9) {
    float se = sigmoidf_(se_param[threadIdx.x]);
    se9[threadIdx.x] = se;
    sl9[threadIdx.x] = -se * LOG2E;
  }
  if (threadIdx.x == 0) g[0] = 0.0f;
  float ab  = attn_b[c];
  float abl = -ab * LOG2E;
  __syncthreads();

  for (int f = threadIdx.x; f < 9 * BROWS * 16; f += 256) {
    int s   = f / 160;
    int rem = f - s * 160;
    int rb  = rem >> 4, sh0 = (rem & 15) << 2;
    int rg  = ((s * 64 * 58255) >> 19) - 1 + rb;
    float4 gv = make_float4(0.0f, 0.0f, 0.0f, 0.0f);
    if ((unsigned)rg < 64u) {
      float se = se9[s], sl = sl9[s];
      float4 xx = *(const float4*)&xp[(rg << 6) + sh0];
      float4 yy = *(const float4*)&yp[(rg << 6) + sh0];
      gv.x = se * xx.x * __builtin_amdgcn_rcpf(1.0f + exp2f(fmaf(yy.x, sl, abl)));
      gv.y = se * xx.y * __builtin_amdgcn_rcpf(1.0f + exp2f(fmaf(yy.y, sl, abl)));
      gv.z = se * xx.z * __builtin_amdgcn_rcpf(1.0f + exp2f(fmaf(yy.z, sl, abl)));
      gv.w = se * xx.w * __builtin_amdgcn_rcpf(1.0f + exp2f(fmaf(yy.w, sl, abl)));
    }
    *(float4*)&g[GOFF + s * BSZ2 + rb * RSTR + sh0] = gv;
  }
  __syncthreads();

  for (int k = 0; k < 16; k++) {
    int wh = (k << 8) | threadIdx.x;
    float m = 0.0f;
#pragma unroll
    for (int s = 0; s < 9; s++) m = fmaxf(m, g[tap_off(s, wh)]);
    yp[wh] = m;
  }
}

extern "C" void kernel_launch(void* const* d_in, const int* in_sizes, int n_in,
                              void* d_out, int out_size, void* d_ws, size_t ws_size,
                              hipStream_t stream) {
  const float* x        = (const float*)d_in[0];
  const float* se_param = (const float*)d_in[1];
  const float* attn_w   = (const float*)d_in[2];
  const float* attn_b   = (const float*)d_in[3];
  float* out = (float*)d_out;

  int B = in_sizes[0] / (CCH * SP);
  unsigned* t32       = (unsigned*)d_ws;
  unsigned short* t16 = (unsigned short*)((char*)d_ws + T16_OFF);
  unsigned short* ybf = (unsigned short*)((char*)d_ws + Y_OFFB);
  size_t need = (size_t)Y_OFFB + (size_t)B * CCH * SP * sizeof(unsigned short);

  if (ws_size >= need) {
    k_conv<<<dim3(TBLK + B * 256), dim3(256), 0, stream>>>(
        x, attn_w, ybf, t32, t16);
    k_attnmax<<<dim3(B * CCH), dim3(256), 0, stream>>>(
        x, ybf, out, se_param, attn_b, (const uint4*)t32, t16);
  } else {
    k_conv_fb<<<dim3(B * 256), dim3(256), 0, stream>>>(x, attn_w, out);
    k_attnmax_fb<<<dim3(B * CCH), dim3(256), 0, stream>>>(
        x, out, se_param, attn_b);
  }
}

// Round 20
// 27.390 us; speedup vs baseline: 5.1888x; 1.2557x over previous
//
#include <hip/hip_runtime.h>

#define CCH 128
#define SP  4096          // 64*64 spatial positions per (b,c)
#define BROWS 10          // band rows rb in [0,10)
#define RSTR 76           // g rb-stride (floats): rows at bank offsets {0,12,24}
#define BSZ2 (BROWS * RSTR)  // 760 floats per band
#define GOFF 16           // g data starts at 16 (64B-aligned); g[0] = sentinel 0
#define GTOT (GOFF + 9 * BSZ2)   // 6856 floats = 27.4 KB
#define T16_OFF 65536     // byte offset of the u16 (s=8) table in d_ws
#define Y_OFFB 73728      // byte offset of bf16 y[b][o][n] in d_ws (8.4 MB)
#define TBLK 80           // table-generator blocks fused into conv grid
#define XTSTR 136         // LDS x_t halfword stride (272B rows)
#define LOG2E 1.4426950408889634f

typedef __attribute__((ext_vector_type(8))) short bf16x8;   // 8 bf16 = 4 VGPRs
typedef __attribute__((ext_vector_type(4))) float f32x4;

__device__ __forceinline__ float sigmoidf_(float z) {
  return 1.0f / (1.0f + __expf(-z));
}

__device__ __forceinline__ unsigned short bf16rne(float f) {
  union { float f; unsigned u; } v; v.f = f;
  return (unsigned short)((v.u + 0x7fffu + ((v.u >> 16) & 1u)) >> 16);
}

__device__ __forceinline__ float bf2f(unsigned short u) {
  union { unsigned u; float f; } v; v.u = (unsigned)u << 16;
  return v.f;
}

// Band-local gather offset for tap s at output wh (g layout [s][rb][sh]):
// GOFF + s*760 + rb*76 + sh, or 0 (sentinel g[0]=0) when source is OOB.
__device__ __forceinline__ int tap_off(int s, int wh) {
  int q  = (s << 12) + wh;     // flat index into torch's reinterpreted view
  int wi = q / 576;  int r  = q - wi * 576;
  int hi = r / 9;    int kk = r - hi * 9;
  int di = kk / 3,   dj = kk - di * 3;
  int sw = wi + di - 1, sh = hi + dj - 1;
  bool valid = ((unsigned)sw < 64u) & ((unsigned)sh < 64u);
  int wilo = (s * 64) / 9;     // first source row of band s
  int rb = sw - wilo + 1;      // in [0,10) for valid sw
  return valid ? (GOFF + s * BSZ2 + rb * RSTR + sh) : 0;
}

// Blocks [0,TBLK): gather tables. Blocks [TBLK,..): MFMA conv -> bf16 y in d_ws.
// Conv geometry = R16 (proven): block = 128o x 32n, 4 waves; wave = 32o x 32n =
// 2 o-tiles x 2 n-tiles; grid 1024 -> 4 blocks/CU, 128B staging segments.
// Only delta vs R16: epilogue stores y as bf16 into d_ws (halves WRITE).
// A/B share k-slot indexing -> invariant to HW k-permutation.
// C/D (m89): col = lane&15 (n), row = (lane>>4)*4 + reg (o).
__global__ __launch_bounds__(256) void k_conv(
    const float* __restrict__ x, const float* __restrict__ attn_w,
    unsigned short* __restrict__ ybf, unsigned* __restrict__ t32,
    unsigned short* __restrict__ t16) {
  int bid = blockIdx.x;
  if (bid < TBLK) {   // table generation: 20480 entries, one per thread
    int i = bid * 256 + threadIdx.x;
    if (i < 4 * SP) {
      int wh = i >> 2, j = i & 3;         // uint4-per-wh packing
      unsigned lo = (unsigned)tap_off(2 * j, wh);
      unsigned hi = (unsigned)tap_off(2 * j + 1, wh);
      t32[i] = lo | (hi << 16);
    } else if (i < 5 * SP) {
      int wh = i & (SP - 1);
      t16[wh] = (unsigned short)tap_off(8, wh);
    }
    return;
  }
  bid -= TBLK;

  __shared__ unsigned short x_t[32 * XTSTR];   // 8704 B

  int b  = bid >> 7;
  int nb = bid & 127;                          // 32n slab
  int lane = threadIdx.x & 63, wv = threadIdx.x >> 6;

  // Staging loads first (16 dwords; lanes 0-31 consecutive n = 128B segments).
  const float* xpb = x + ((size_t)b << 19) + (nb << 5);
  int n_st  = threadIdx.x & 31;
  int c_st  = (threadIdx.x >> 5) << 2;
  float xv[16];
#pragma unroll
  for (int g = 0; g < 4; g++) {
    int c0 = c_st + (g << 5);
#pragma unroll
    for (int i = 0; i < 4; i++)
      xv[g * 4 + i] = xpb[((size_t)(c0 + i) << 12) + n_st];
  }

  // A-fragments from fp32 w (L2-hot 64KB): lane l holds
  // A[o = ot*16 + (l&15)][k = ks*32 + (l>>4)*8 .. +7], converted to bf16.
  bf16x8 afrag[2][4];
#pragma unroll
  for (int ot = 0; ot < 2; ot++)
#pragma unroll
    for (int ks = 0; ks < 4; ks++) {
      int o = (wv << 5) + (ot << 4) + (lane & 15);
      int k = (ks << 5) + ((lane >> 4) << 3);
      const float4* wp = (const float4*)&attn_w[(o << 7) + k];
      float4 a0 = wp[0], a1 = wp[1];
      bf16x8 f;
      f[0] = (short)bf16rne(a0.x); f[1] = (short)bf16rne(a0.y);
      f[2] = (short)bf16rne(a0.z); f[3] = (short)bf16rne(a0.w);
      f[4] = (short)bf16rne(a1.x); f[5] = (short)bf16rne(a1.y);
      f[6] = (short)bf16rne(a1.z); f[7] = (short)bf16rne(a1.w);
      afrag[ot][ks] = f;
    }

  // Convert + write staged x into transposed bf16 LDS x_t[n][k].
#pragma unroll
  for (int g = 0; g < 4; g++) {
    int c0 = c_st + (g << 5);
    union { unsigned short s[2]; unsigned u; } p0, p1;
    p0.s[0] = bf16rne(xv[g * 4 + 0]); p0.s[1] = bf16rne(xv[g * 4 + 1]);
    p1.s[0] = bf16rne(xv[g * 4 + 2]); p1.s[1] = bf16rne(xv[g * 4 + 3]);
    *(uint2*)&x_t[n_st * XTSTR + c0] = make_uint2(p0.u, p1.u);
  }
  __syncthreads();

  f32x4 acc[2][2] = {};
#pragma unroll
  for (int ks = 0; ks < 4; ks++) {
    bf16x8 bfrag[2];
#pragma unroll
    for (int nt = 0; nt < 2; nt++) {
      int n = (nt << 4) + (lane & 15);
      int k = (ks << 5) + ((lane >> 4) << 3);
      bfrag[nt] = *(const bf16x8*)&x_t[n * XTSTR + k];   // ds_read_b128
    }
#pragma unroll
    for (int ot = 0; ot < 2; ot++)
#pragma unroll
      for (int nt = 0; nt < 2; nt++)
        acc[ot][nt] = __builtin_amdgcn_mfma_f32_16x16x32_bf16(
            afrag[ot][ks], bfrag[nt], acc[ot][nt], 0, 0, 0);
  }

  // Epilogue: acc[ot][nt][r] -> bf16 y[o][n], o = base + (lane>>4)*4 + r.
  unsigned short* yb = ybf + ((size_t)b << 19) + (nb << 5);
#pragma unroll
  for (int ot = 0; ot < 2; ot++) {
    int ob = (wv << 5) + (ot << 4) + ((lane >> 4) << 2);
#pragma unroll
    for (int nt = 0; nt < 2; nt++) {
      int n = (nt << 4) + (lane & 15);
#pragma unroll
      for (int r = 0; r < 4; r++)
        yb[((size_t)(ob + r) << 12) + n] = bf16rne(acc[ot][nt][r]);
    }
  }
}

// out[b,c,wh] = max_s G_s[src(s,wh)], G_s[p] = se[s]*x[p]*sigmoid(se[s]*y[p]+ab).
// y read as bf16 from d_ws; result written once to d_out.
__global__ __launch_bounds__(256) void k_attnmax(
    const float* __restrict__ x, const unsigned short* __restrict__ ybf,
    float* __restrict__ out,
    const float* __restrict__ se_param, const float* __restrict__ attn_b,
    const uint4* __restrict__ t32, const unsigned short* __restrict__ t16) {
  __shared__ float g[GTOT];
  __shared__ float se9[16], sl9[16];

  int bc = blockIdx.x;            // b*128 + c
  int c  = bc & (CCH - 1);
  const float* xp = x + ((size_t)bc << 12);
  const unsigned short* yp = ybf + ((size_t)bc << 12);
  float* op = out + ((size_t)bc << 12);

  if (threadIdx.x < 9) {
    float se = sigmoidf_(se_param[threadIdx.x]);
    se9[threadIdx.x] = se;
    sl9[threadIdx.x] = -se * LOG2E;
  }
  if (threadIdx.x == 0) g[0] = 0.0f;
  float ab  = attn_b[c];
  float abl = -ab * LOG2E;
  __syncthreads();

  // Phase 1: 1440 float4 units -> (s, rb, sh0). Source row rg = wilo(s)-1+rb.
  for (int f = threadIdx.x; f < 9 * BROWS * 16; f += 256) {
    int s   = f / 160;
    int rem = f - s * 160;
    int rb  = rem >> 4, sh0 = (rem & 15) << 2;
    int rg  = ((s * 64 * 58255) >> 19) - 1 + rb;   // wilo(s) = (s*64)/9
    float4 gv = make_float4(0.0f, 0.0f, 0.0f, 0.0f);
    if ((unsigned)rg < 64u) {
      float se = se9[s], sl = sl9[s];
      float4 xx = *(const float4*)&xp[(rg << 6) + sh0];     // coalesced
      ushort4 yu = *(const ushort4*)&yp[(rg << 6) + sh0];   // bf16 y
      gv.x = se * xx.x * __builtin_amdgcn_rcpf(1.0f + exp2f(fmaf(bf2f(yu.x), sl, abl)));
      gv.y = se * xx.y * __builtin_amdgcn_rcpf(1.0f + exp2f(fmaf(bf2f(yu.y), sl, abl)));
      gv.z = se * xx.z * __builtin_amdgcn_rcpf(1.0f + exp2f(fmaf(bf2f(yu.z), sl, abl)));
      gv.w = se * xx.w * __builtin_amdgcn_rcpf(1.0f + exp2f(fmaf(bf2f(yu.w), sl, abl)));
    }
    *(float4*)&g[GOFF + s * BSZ2 + rb * RSTR + sh0] = gv;   // b128, aligned
  }
  __syncthreads();

  // Phase 2: gather + max -> d_out.
  for (int k = 0; k < 16; k++) {
    int wh = (k << 8) | threadIdx.x;
    uint4 p = t32[wh];                 // 16B coalesced: taps 0..7
    int p8  = t16[wh];
    float m0 = fmaxf(g[p.x & 0xffffu], g[p.x >> 16]);
    float m1 = fmaxf(g[p.y & 0xffffu], g[p.y >> 16]);
    float m2 = fmaxf(g[p.z & 0xffffu], g[p.z >> 16]);
    float m3 = fmaxf(g[p.w & 0xffffu], g[p.w >> 16]);
    op[wh] = fmaxf(fmaxf(fmaxf(m0, m1), fmaxf(m2, m3)), g[p8]);
  }
}

// ---------------- fallback path (no workspace): fp32 y via d_out ----------------
__global__ __launch_bounds__(256) void k_conv_fb(
    const float* __restrict__ x, const float* __restrict__ attn_w,
    float* __restrict__ y) {
  __shared__ unsigned short x_t[32 * XTSTR];
  int bid = blockIdx.x;
  int b  = bid >> 7;
  int nb = bid & 127;
  int lane = threadIdx.x & 63, wv = threadIdx.x >> 6;

  const float* xpb = x + ((size_t)b << 19) + (nb << 5);
  int n_st = threadIdx.x & 31;
  int c_st = (threadIdx.x >> 5) << 2;
  float xv[16];
#pragma unroll
  for (int g = 0; g < 4; g++) {
    int c0 = c_st + (g << 5);
#pragma unroll
    for (int i = 0; i < 4; i++)
      xv[g * 4 + i] = xpb[((size_t)(c0 + i) << 12) + n_st];
  }

  bf16x8 afrag[2][4];
#pragma unroll
  for (int ot = 0; ot < 2; ot++)
#pragma unroll
    for (int ks = 0; ks < 4; ks++) {
      int o = (wv << 5) + (ot << 4) + (lane & 15);
      int k = (ks << 5) + ((lane >> 4) << 3);
      const float4* wp = (const float4*)&attn_w[(o << 7) + k];
      float4 a0 = wp[0], a1 = wp[1];
      bf16x8 f;
      f[0] = (short)bf16rne(a0.x); f[1] = (short)bf16rne(a0.y);
      f[2] = (short)bf16rne(a0.z); f[3] = (short)bf16rne(a0.w);
      f[4] = (short)bf16rne(a1.x); f[5] = (short)bf16rne(a1.y);
      f[6] = (short)bf16rne(a1.z); f[7] = (short)bf16rne(a1.w);
      afrag[ot][ks] = f;
    }

#pragma unroll
  for (int g = 0; g < 4; g++) {
    int c0 = c_st + (g << 5);
    union { unsigned short s[2]; unsigned u; } p0, p1;
    p0.s[0] = bf16rne(xv[g * 4 + 0]); p0.s[1] = bf16rne(xv[g * 4 + 1]);
    p1.s[0] = bf16rne(xv[g * 4 + 2]); p1.s[1] = bf16rne(xv[g * 4 + 3]);
    *(uint2*)&x_t[n_st * XTSTR + c0] = make_uint2(p0.u, p1.u);
  }
  __syncthreads();

  f32x4 acc[2][2] = {};
#pragma unroll
  for (int ks = 0; ks < 4; ks++) {
    bf16x8 bfrag[2];
#pragma unroll
    for (int nt = 0; nt < 2; nt++) {
      int n = (nt << 4) + (lane & 15);
      int k = (ks << 5) + ((lane >> 4) << 3);
      bfrag[nt] = *(const bf16x8*)&x_t[n * XTSTR + k];
    }
#pragma unroll
    for (int ot = 0; ot < 2; ot++)
#pragma unroll
      for (int nt = 0; nt < 2; nt++)
        acc[ot][nt] = __builtin_amdgcn_mfma_f32_16x16x32_bf16(
            afrag[ot][ks], bfrag[nt], acc[ot][nt], 0, 0, 0);
  }

  float* yb = y + ((size_t)b << 19) + (nb << 5);
#pragma unroll
  for (int ot = 0; ot < 2; ot++) {
    int ob = (wv << 5) + (ot << 4) + ((lane >> 4) << 2);
#pragma unroll
    for (int nt = 0; nt < 2; nt++) {
      int n = (nt << 4) + (lane & 15);
#pragma unroll
      for (int r = 0; r < 4; r++)
        yb[((size_t)(ob + r) << 12) + n] = acc[ot][nt][r];
    }
  }
}

__global__ __launch_bounds__(256) void k_attnmax_fb(
    const float* __restrict__ x, float* __restrict__ yo,
    const float* __restrict__ se_param, const float* __restrict__ attn_b) {
  __shared__ float g[GTOT];
  __shared__ float se9[16], sl9[16];

  int bc = blockIdx.x;
  int c  = bc & (CCH - 1);
  const float* xp = x  + ((size_t)bc << 12);
  float*       yp = yo + ((size_t)bc << 12);

  if (threadIdx.x < 9) {
    float se = sigmoidf_(se_param[threadIdx.x]);
    se9[threadIdx.x] = se;
    sl9[threadIdx.x] = -se * LOG2E;
  }
  if (threadIdx.x == 0) g[0] = 0.0f;
  float ab  = attn_b[c];
  float abl = -ab * LOG2E;
  __syncthreads();

  for (int f = threadIdx.x; f < 9 * BROWS * 16; f += 256) {
    int s   = f / 160;
    int rem = f - s * 160;
    int rb  = rem >> 4, sh0 = (rem & 15) << 2;
    int rg  = ((s * 64 * 58255) >> 19) - 1 + rb;
    float4 gv = make_float4(0.0f, 0.0f, 0.0f, 0.0f);
    if ((unsigned)rg < 64u) {
      float se = se9[s], sl = sl9[s];
      float4 xx = *(const float4*)&xp[(rg << 6) + sh0];
      float4 yy = *(const float4*)&yp[(rg << 6) + sh0];
      gv.x = se * xx.x * __builtin_amdgcn_rcpf(1.0f + exp2f(fmaf(yy.x, sl, abl)));
      gv.y = se * xx.y * __builtin_amdgcn_rcpf(1.0f + exp2f(fmaf(yy.y, sl, abl)));
      gv.z = se * xx.z * __builtin_amdgcn_rcpf(1.0f + exp2f(fmaf(yy.z, sl, abl)));
      gv.w = se * xx.w * __builtin_amdgcn_rcpf(1.0f + exp2f(fmaf(yy.w, sl, abl)));
    }
    *(float4*)&g[GOFF + s * BSZ2 + rb * RSTR + sh0] = gv;
  }
  __syncthreads();

  for (int k = 0; k < 16; k++) {
    int wh = (k << 8) | threadIdx.x;
    float m = 0.0f;
#pragma unroll
    for (int s = 0; s < 9; s++) m = fmaxf(m, g[tap_off(s, wh)]);
    yp[wh] = m;
  }
}

extern "C" void kernel_launch(void* const* d_in, const int* in_sizes, int n_in,
                              void* d_out, int out_size, void* d_ws, size_t ws_size,
                              hipStream_t stream) {
  const float* x        = (const float*)d_in[0];
  const float* se_param = (const float*)d_in[1];
  const float* attn_w   = (const float*)d_in[2];
  const float* attn_b   = (const float*)d_in[3];
  float* out = (float*)d_out;

  int B = in_sizes[0] / (CCH * SP);
  unsigned* t32       = (unsigned*)d_ws;
  unsigned short* t16 = (unsigned short*)((char*)d_ws + T16_OFF);
  unsigned short* ybf = (unsigned short*)((char*)d_ws + Y_OFFB);
  size_t need = (size_t)Y_OFFB + (size_t)B * CCH * SP * sizeof(unsigned short);

  if (ws_size >= need) {
    k_conv<<<dim3(TBLK + B * 128), dim3(256), 0, stream>>>(
        x, attn_w, ybf, t32, t16);
    k_attnmax<<<dim3(B * CCH), dim3(256), 0, stream>>>(
        x, ybf, out, se_param, attn_b, (const uint4*)t32, t16);
  } else {
    k_conv_fb<<<dim3(B * 128), dim3(256), 0, stream>>>(x, attn_w, out);
    k_attnmax_fb<<<dim3(B * CCH), dim3(256), 0, stream>>>(
        x, out, se_param, attn_b);
  }
}